// Round 11
// baseline (340.259 us; speedup 1.0000x reference)
//
#include <hip/hip_runtime.h>
#include <stdint.h>

typedef __bf16 bf16_t;
typedef __bf16 bf16x8 __attribute__((ext_vector_type(8)));
typedef __bf16 bf16x4 __attribute__((ext_vector_type(4)));
typedef float f32x4 __attribute__((ext_vector_type(4)));

__device__ __forceinline__ f32x4 mfma16(bf16x8 a, bf16x8 b, f32x4 c) {
  return __builtin_amdgcn_mfma_f32_16x16x32_bf16(a, b, c, 0, 0, 0);
}

__device__ __forceinline__ void g2l16(const void* g, void* l) {
  __builtin_amdgcn_global_load_lds((const __attribute__((address_space(1))) void*)g,
                                   (__attribute__((address_space(3))) void*)l, 16, 0, 0);
}

#define FENCE() asm volatile("" ::: "memory")

// ---------------- all f32 -> bf16 converts, one launch ----------------
// blocks 0..8191: x (16.78M elems). 8192..10239: four 1M-elem weights.
__global__ void __launch_bounds__(256) cvt_all(const float* __restrict__ x,
                                               const float* __restrict__ Wq,
                                               const float* __restrict__ Wk,
                                               const float* __restrict__ Wv,
                                               const float* __restrict__ Wo,
                                               bf16_t* __restrict__ xb,
                                               bf16_t* __restrict__ wqk,
                                               bf16_t* __restrict__ wvb,
                                               bf16_t* __restrict__ wob) {
  const int id = blockIdx.x;
  const float* src;
  bf16_t* dst;
  long off;
  if (id < 8192) {
    src = x; dst = xb; off = (long)id;
  } else {
    const int seg = (id - 8192) >> 9;
    off = (id - 8192) & 511;
    if (seg == 0)      { src = Wq; dst = wqk; }
    else if (seg == 1) { src = Wk; dst = wqk + 1048576; }
    else if (seg == 2) { src = Wv; dst = wvb; }
    else               { src = Wo; dst = wob; }
  }
  long i = (off * 256 + threadIdx.x) * 8;
  float4 f0 = *(const float4*)(src + i);
  float4 f1 = *(const float4*)(src + i + 4);
  bf16x8 v;
  v[0] = (bf16_t)f0.x; v[1] = (bf16_t)f0.y; v[2] = (bf16_t)f0.z; v[3] = (bf16_t)f0.w;
  v[4] = (bf16_t)f1.x; v[5] = (bf16_t)f1.y; v[6] = (bf16_t)f1.z; v[7] = (bf16_t)f1.w;
  *(bf16x8*)(dst + i) = v;
}

// ------- 256x256 2-phase GEMM core (round-6 proven body, verbatim) -------
template <typename OutT>
__device__ __forceinline__ void gemm_core(const bf16_t* __restrict__ A,
                                          const bf16_t* __restrict__ Bt,
                                          OutT* __restrict__ C,
                                          int N, int K, int NBN, int nseg, int flat,
                                          char* smem) {
  const int t = threadIdx.x;
  const int w = t >> 6, l = t & 63;
  const int lr = l & 15, lg = l >> 4;
  const int wm = w >> 2, wn = w & 3;

  const int swz = (flat & 7) * (nseg >> 3) + (flat >> 3);
  const int bm = swz / NBN, bn = swz % NBN;
  const long rowA0 = (long)bm * 256;
  const long colC0 = (long)bn * 256;
  const int KT = K >> 6;

  const int colSwz = ((l & 7) ^ (l >> 3)) * 8;
  const bf16_t* gA = A + (rowA0 + w * 32 + (l >> 3)) * (long)K + colSwz;
  const bf16_t* gB = Bt + (colC0 + w * 32 + (l >> 3)) * (long)K + colSwz;
  const long K8 = (long)K * 8;

  const int sx0 = (lg ^ (lr & 7)) * 16;
  const int sx1 = ((4 + lg) ^ (lr & 7)) * 16;
  const int aRow = (wm * 128 + lr) * 128;
  const int bRow = 32768 + (wn * 64 + lr) * 128;

  f32x4 acc[8][4] = {};

#define STAGE_A(buf, kt)                                          \
  {                                                               \
    char* _d = smem + (buf) * 65536 + w * 4096;                   \
    const long _ko = (long)(kt) * 64;                             \
    g2l16(gA + _ko, _d);                                          \
    g2l16(gA + K8 + _ko, _d + 1024);                              \
    g2l16(gA + 2 * K8 + _ko, _d + 2048);                          \
    g2l16(gA + 3 * K8 + _ko, _d + 3072);                          \
  }
#define STAGE_B(buf, kt)                                          \
  {                                                               \
    char* _d = smem + (buf) * 65536 + 32768 + w * 4096;           \
    const long _ko = (long)(kt) * 64;                             \
    g2l16(gB + _ko, _d);                                          \
    g2l16(gB + K8 + _ko, _d + 1024);                              \
    g2l16(gB + 2 * K8 + _ko, _d + 2048);                          \
    g2l16(gB + 3 * K8 + _ko, _d + 3072);                          \
  }

  STAGE_A(0, 0); STAGE_B(0, 0);
  FENCE();
  asm volatile("s_waitcnt vmcnt(0)" ::: "memory");
  __builtin_amdgcn_s_barrier();

  for (int kt = 0; kt < KT; ++kt) {
    const char* sb = smem + (kt & 1) * 65536;
    const int nb = (kt + 1) & 1;
    const bool ds = (kt + 1) < KT;

    bf16x8 bfr[4][2];

    {
      bf16x8 a0[4][2];
#pragma unroll
      for (int j = 0; j < 4; ++j) {
        bfr[j][0] = *(const bf16x8*)(sb + bRow + j * 2048 + sx0);
        bfr[j][1] = *(const bf16x8*)(sb + bRow + j * 2048 + sx1);
      }
#pragma unroll
      for (int i = 0; i < 4; ++i) {
        a0[i][0] = *(const bf16x8*)(sb + aRow + i * 2048 + sx0);
        a0[i][1] = *(const bf16x8*)(sb + aRow + i * 2048 + sx1);
      }
      if (ds) STAGE_A(nb, kt + 1);
      FENCE();
      __builtin_amdgcn_s_barrier();
      asm volatile("s_waitcnt lgkmcnt(0)" ::: "memory");
      __builtin_amdgcn_sched_barrier(0);
      __builtin_amdgcn_s_setprio(1);
#pragma unroll
      for (int i = 0; i < 4; ++i)
#pragma unroll
        for (int j = 0; j < 4; ++j) {
          acc[i][j] = mfma16(a0[i][0], bfr[j][0], acc[i][j]);
          acc[i][j] = mfma16(a0[i][1], bfr[j][1], acc[i][j]);
        }
      __builtin_amdgcn_s_setprio(0);
      __builtin_amdgcn_sched_barrier(0);
      FENCE();
      __builtin_amdgcn_s_barrier();
    }

    {
      bf16x8 a1[4][2];
#pragma unroll
      for (int i = 0; i < 4; ++i) {
        a1[i][0] = *(const bf16x8*)(sb + aRow + (4 + i) * 2048 + sx0);
        a1[i][1] = *(const bf16x8*)(sb + aRow + (4 + i) * 2048 + sx1);
      }
      if (ds) STAGE_B(nb, kt + 1);
      FENCE();
      __builtin_amdgcn_s_barrier();
      asm volatile("s_waitcnt lgkmcnt(0)" ::: "memory");
      __builtin_amdgcn_sched_barrier(0);
      __builtin_amdgcn_s_setprio(1);
#pragma unroll
      for (int i = 0; i < 4; ++i)
#pragma unroll
        for (int j = 0; j < 4; ++j) {
          acc[4 + i][j] = mfma16(a1[i][0], bfr[j][0], acc[4 + i][j]);
          acc[4 + i][j] = mfma16(a1[i][1], bfr[j][1], acc[4 + i][j]);
        }
      __builtin_amdgcn_s_setprio(0);
      __builtin_amdgcn_sched_barrier(0);
      FENCE();
      if (ds) {
        asm volatile("s_waitcnt vmcnt(0)" ::: "memory");
      }
      __builtin_amdgcn_s_barrier();
    }
  }
#undef STAGE_A
#undef STAGE_B

#pragma unroll
  for (int i = 0; i < 8; ++i)
#pragma unroll
    for (int j = 0; j < 4; ++j)
#pragma unroll
      for (int r = 0; r < 4; ++r) {
        long row = rowA0 + wm * 128 + i * 16 + lg * 4 + r;
        long col = colC0 + wn * 64 + j * 16 + lr;
        C[row * (long)N + col] = (OutT)acc[i][j][r];
      }
}

// merged QK + Vt projections
__global__ void __launch_bounds__(512, 2) gemm_qkvt(const bf16_t* __restrict__ xb,
                                                    const bf16_t* __restrict__ wqk,
                                                    bf16_t* __restrict__ qk,
                                                    const bf16_t* __restrict__ wvb,
                                                    bf16_t* __restrict__ vt) {
  extern __shared__ char smem[];
  const int id = blockIdx.x;
  if (id < 512) {
    gemm_core<bf16_t>(xb, wqk, qk, 2048, 1024, 8, 512, id, smem);
  } else {
    gemm_core<bf16_t>(wvb, xb, vt, 16384, 1024, 64, 256, id - 512, smem);
  }
}

// output projection
__global__ void __launch_bounds__(512, 2) gemm_out(const bf16_t* __restrict__ att,
                                                   const bf16_t* __restrict__ wob,
                                                   float* __restrict__ out) {
  extern __shared__ char smem[];
  gemm_core<float>(att, wob, out, 1024, 1024, 4, 256, blockIdx.x, smem);
}

// ---------------- sliding-window attention, zero-staging (direct K/V) ----------------
// K and V fragments are read per-lane straight from global (qk / vt). Each chunk's
// K,V are 16 KB apiece: L1-resident within a block (8 waves reuse), L2-resident
// across the 3 neighboring-n blocks (XCD-chunked launch order). Removes ALL LDS
// staging, vmcnt gating and per-chunk block barriers (guide common-mistake #7).
// Remaining sync: one prologue __syncthreads (bias), wave-local lgkm fence between
// P-write and P-read (per-wave Psw region, proven pattern).
__global__ void __launch_bounds__(512, 4) swa5(const bf16_t* __restrict__ QK,
                                               const bf16_t* __restrict__ VT,
                                               const float* __restrict__ amask,
                                               bf16_t* __restrict__ Att) {
  extern __shared__ char lds[];
  float* bias = (float*)lds;                     // up to 3*128 f32 = 1536 B
  const int t = threadIdx.x, w = t >> 6, l = t & 63, lr = l & 15, lg = l >> 4;
  char* Psw = lds + 2048 + w * 4352;             // per-wave [16 q][272 B]

  const int idx = (blockIdx.x & 7) * 256 + (blockIdx.x >> 3);
  const int n = idx & 31, h = (idx >> 5) & 15, b = idx >> 9;
  const long rowQ = (long)b * 4096 + n * 128;

  // Q as B-operand frags (col = q = lr, k elems = d at lg*8)
  bf16x8 qf[2];
#pragma unroll
  for (int ks = 0; ks < 2; ++ks)
    qf[ks] = *(const bf16x8*)&QK[(rowQ + w * 16 + lr) * 2048 + h * 64 + ks * 32 + lg * 8];

  f32x4 oT[4] = {};
  float l_run = 0.f;

  const int kcLo = (n > 0) ? n - 1 : 0;
  const int kcHi = (n < 31) ? n + 1 : 31;
  const long kbase0 = (long)b * 4096 + (long)kcLo * 128;
  const int nch = kcHi - kcLo + 1;

  if (t < nch * 32) {
    float4 mv = *(const float4*)(amask + kbase0 + t * 4);
    float4 bv;
    bv.x = mv.x > 0.f ? 0.f : -1e30f;
    bv.y = mv.y > 0.f ? 0.f : -1e30f;
    bv.z = mv.z > 0.f ? 0.f : -1e30f;
    bv.w = mv.w > 0.f ? 0.f : -1e30f;
    *(float4*)&bias[t * 4] = bv;
  }
  __syncthreads();

  const float c1 = 0.18033688011112042f;  // 0.125 * log2(e)

  for (int c = 0; c < nch; ++c) {
    const bf16_t* Kc = QK + (kbase0 + (long)c * 128) * 2048 + 1024 + h * 64;
    const bf16_t* Vc = VT + (long)h * 64 * 16384 + kbase0 + (long)c * 128;

    // ---- QK^T -> S^T, K direct from global (L1/L2) ----
    f32x4 s[8];
#pragma unroll
    for (int kb = 0; kb < 8; ++kb) {
      f32x4 z = {};
#pragma unroll
      for (int ks = 0; ks < 2; ++ks) {
        bf16x8 kA = *(const bf16x8*)&Kc[(kb * 16 + lr) * 2048 + ks * 32 + lg * 8];
        z = mfma16(kA, qf[ks], z);
      }
      s[kb] = z;
    }

    // ---- softmax numerator: p = 2^(s*c1 + bias'), no max subtraction ----
    float rs = 0.f;
#pragma unroll
    for (int kb = 0; kb < 8; ++kb) {
      f32x4 bb = *(const f32x4*)&bias[c * 128 + kb * 16 + lg * 4];
#pragma unroll
      for (int r = 0; r < 4; ++r) {
        float p = __builtin_amdgcn_exp2f(s[kb][r] * c1 + bb[r]);
        s[kb][r] = p;
        rs += p;
      }
    }
    rs += __shfl_xor(rs, 16);
    rs += __shfl_xor(rs, 32);
    l_run += rs;

    // ---- P^T -> per-wave LDS (b64), wave-local fence before cross-lane reads ----
#pragma unroll
    for (int kb = 0; kb < 8; ++kb) {
      bf16x4 pv;
      pv[0] = (bf16_t)s[kb][0]; pv[1] = (bf16_t)s[kb][1];
      pv[2] = (bf16_t)s[kb][2]; pv[3] = (bf16_t)s[kb][3];
      *(bf16x4*)(Psw + lr * 272 + kb * 32 + lg * 8) = pv;
    }
    asm volatile("s_waitcnt lgkmcnt(0)" ::: "memory");
    __builtin_amdgcn_sched_barrier(0);

    // ---- PV: O^T[d,q] += V^T x P^T, V direct from global (L1/L2) ----
#pragma unroll
    for (int ks = 0; ks < 4; ++ks) {
      bf16x8 pB = *(const bf16x8*)(Psw + lr * 272 + ks * 64 + lg * 16);
#pragma unroll
      for (int df = 0; df < 4; ++df) {
        bf16x8 vA = *(const bf16x8*)&Vc[(long)(df * 16 + lr) * 16384 + ks * 32 + lg * 8];
        oT[df] = mfma16(vA, pB, oT[df]);
      }
    }
    // Psw reuse next chunk: wave-local WAR; the next P-write is ordered behind
    // these pB ds_reads by the DS pipe (in-order per wave) -- and the lgkm fence
    // above each chunk's PV guarantees visibility. No block barrier needed.
  }

  // ---- epilogue: normalize, transpose O^T via per-wave Psw, coalesced store ----
  asm volatile("s_waitcnt lgkmcnt(0)" ::: "memory");  // last pB reads done (WAR)
  __builtin_amdgcn_sched_barrier(0);
  float inv = 1.f / l_run;
#pragma unroll
  for (int df = 0; df < 4; ++df) {
    bf16x4 ov;
#pragma unroll
    for (int r = 0; r < 4; ++r) ov[r] = (bf16_t)(oT[df][r] * inv);
    *(bf16x4*)(Psw + lr * 272 + df * 32 + lg * 8) = ov;
  }
  asm volatile("s_waitcnt lgkmcnt(0)" ::: "memory");
  __builtin_amdgcn_sched_barrier(0);
  const char* myP = lds + 2048 + w * 4352;
  bf16x8 r0 = *(const bf16x8*)(myP + (l >> 2) * 272 + (l & 3) * 32);
  bf16x8 r1 = *(const bf16x8*)(myP + (l >> 2) * 272 + (l & 3) * 32 + 16);
  long orow = rowQ + w * 16 + (l >> 2);
  bf16_t* op = Att + orow * 1024 + h * 64 + (l & 3) * 16;
  *(bf16x8*)op = r0;
  *(bf16x8*)(op + 8) = r1;
}

// ---------------- launch ----------------
extern "C" void kernel_launch(void* const* d_in, const int* in_sizes, int n_in,
                              void* d_out, int out_size, void* d_ws, size_t ws_size,
                              hipStream_t stream) {
  const float* x  = (const float*)d_in[0];
  const float* am = (const float*)d_in[1];
  const float* Wq = (const float*)d_in[2];
  const float* Wk = (const float*)d_in[3];
  const float* Wv = (const float*)d_in[4];
  const float* Wo = (const float*)d_in[5];
  float* out = (float*)d_out;

  char* ws = (char*)d_ws;
  bf16_t* qk  = (bf16_t*)ws;                        // [16384,2048] = 67108864 B
  bf16_t* vt  = (bf16_t*)(ws + 67108864);           // [1024,16384] = 33554432 B
  bf16_t* xbx = (bf16_t*)(ws + 100663296);          // [16384,1024] bf16 x; reused as attended
  bf16_t* wqk = (bf16_t*)(ws + 134217728);          // [2048,1024] rows: Wq, Wk
  bf16_t* wvb = (bf16_t*)(ws + 138412032);          // [1024,1024] Wv
  bf16_t* wob = (bf16_t*)(ws + 140509184);          // [1024,1024] Wo

  const int kSmemG = 131072;  // 2 x 64KB double buffer
  hipFuncSetAttribute(reinterpret_cast<const void*>(&gemm_qkvt),
                      hipFuncAttributeMaxDynamicSharedMemorySize, kSmemG);
  hipFuncSetAttribute(reinterpret_cast<const void*>(&gemm_out),
                      hipFuncAttributeMaxDynamicSharedMemorySize, kSmemG);
  const int kSmemS = 36864;  // bias 2KB + Psw 8*4352
  hipFuncSetAttribute(reinterpret_cast<const void*>(&swa5),
                      hipFuncAttributeMaxDynamicSharedMemorySize, kSmemS);

  cvt_all<<<10240, 256, 0, stream>>>(x, Wq, Wk, Wv, Wo, xbx, wqk, wvb, wob);

  // merged: QK projection (512 blocks) + V^T projection (256 blocks)
  gemm_qkvt<<<768, 512, kSmemG, stream>>>(xbx, wqk, qk, wvb, vt);

  // local attention -> attended [16384,1024] bf16 (overwrites xbx)
  swa5<<<2048, 512, kSmemS, stream>>>(qk, vt, am, xbx);

  // output projection -> d_out f32
  gemm_out<<<256, 512, kSmemG, stream>>>(xbx, wob, out);
}

// Round 12
// 216.521 us; speedup vs baseline: 1.5715x; 1.5715x over previous
//
#include <hip/hip_runtime.h>
#include <stdint.h>

typedef __bf16 bf16_t;
typedef __bf16 bf16x8 __attribute__((ext_vector_type(8)));
typedef __bf16 bf16x4 __attribute__((ext_vector_type(4)));
typedef float f32x4 __attribute__((ext_vector_type(4)));

__device__ __forceinline__ f32x4 mfma16(bf16x8 a, bf16x8 b, f32x4 c) {
  return __builtin_amdgcn_mfma_f32_16x16x32_bf16(a, b, c, 0, 0, 0);
}

__device__ __forceinline__ void g2l16(const void* g, void* l) {
  __builtin_amdgcn_global_load_lds((const __attribute__((address_space(1))) void*)g,
                                   (__attribute__((address_space(3))) void*)l, 16, 0, 0);
}

#define FENCE() asm volatile("" ::: "memory")

// ---------------- all f32 -> bf16 converts, one launch ----------------
__global__ void __launch_bounds__(256) cvt_all(const float* __restrict__ x,
                                               const float* __restrict__ Wq,
                                               const float* __restrict__ Wk,
                                               const float* __restrict__ Wv,
                                               const float* __restrict__ Wo,
                                               bf16_t* __restrict__ xb,
                                               bf16_t* __restrict__ wqk,
                                               bf16_t* __restrict__ wvb,
                                               bf16_t* __restrict__ wob) {
  const int id = blockIdx.x;
  const float* src;
  bf16_t* dst;
  long off;
  if (id < 8192) {
    src = x; dst = xb; off = (long)id;
  } else {
    const int seg = (id - 8192) >> 9;
    off = (id - 8192) & 511;
    if (seg == 0)      { src = Wq; dst = wqk; }
    else if (seg == 1) { src = Wk; dst = wqk + 1048576; }
    else if (seg == 2) { src = Wv; dst = wvb; }
    else               { src = Wo; dst = wob; }
  }
  long i = (off * 256 + threadIdx.x) * 8;
  float4 f0 = *(const float4*)(src + i);
  float4 f1 = *(const float4*)(src + i + 4);
  bf16x8 v;
  v[0] = (bf16_t)f0.x; v[1] = (bf16_t)f0.y; v[2] = (bf16_t)f0.z; v[3] = (bf16_t)f0.w;
  v[4] = (bf16_t)f1.x; v[5] = (bf16_t)f1.y; v[6] = (bf16_t)f1.z; v[7] = (bf16_t)f1.w;
  *(bf16x8*)(dst + i) = v;
}

// ------- 256x256 2-phase GEMM core -------
// A/B vs round 10: the explicit `s_waitcnt lgkmcnt(0)` + sched_barrier(0) drains
// before/after each MFMA cluster are REMOVED. The compiler then emits fine-grained
// counted lgkmcnt waits interleaved with the MFMAs (m97-verified), so early MFMAs
// overlap late ds_reads. Sync safety unchanged: each wave's reads are consumed by
// its own MFMAs (auto-waited) and complete before the phase-end barrier; DMA/WAR
// hazards still guarded by the identical barrier + vmcnt structure.
template <typename OutT>
__device__ __forceinline__ void gemm_core(const bf16_t* __restrict__ A,
                                          const bf16_t* __restrict__ Bt,
                                          OutT* __restrict__ C,
                                          int N, int K, int NBN, int nseg, int flat,
                                          char* smem) {
  const int t = threadIdx.x;
  const int w = t >> 6, l = t & 63;
  const int lr = l & 15, lg = l >> 4;
  const int wm = w >> 2, wn = w & 3;

  const int swz = (flat & 7) * (nseg >> 3) + (flat >> 3);
  const int bm = swz / NBN, bn = swz % NBN;
  const long rowA0 = (long)bm * 256;
  const long colC0 = (long)bn * 256;
  const int KT = K >> 6;

  const int colSwz = ((l & 7) ^ (l >> 3)) * 8;
  const bf16_t* gA = A + (rowA0 + w * 32 + (l >> 3)) * (long)K + colSwz;
  const bf16_t* gB = Bt + (colC0 + w * 32 + (l >> 3)) * (long)K + colSwz;
  const long K8 = (long)K * 8;

  const int sx0 = (lg ^ (lr & 7)) * 16;
  const int sx1 = ((4 + lg) ^ (lr & 7)) * 16;
  const int aRow = (wm * 128 + lr) * 128;
  const int bRow = 32768 + (wn * 64 + lr) * 128;

  f32x4 acc[8][4] = {};

#define STAGE_A(buf, kt)                                          \
  {                                                               \
    char* _d = smem + (buf) * 65536 + w * 4096;                   \
    const long _ko = (long)(kt) * 64;                             \
    g2l16(gA + _ko, _d);                                          \
    g2l16(gA + K8 + _ko, _d + 1024);                              \
    g2l16(gA + 2 * K8 + _ko, _d + 2048);                          \
    g2l16(gA + 3 * K8 + _ko, _d + 3072);                          \
  }
#define STAGE_B(buf, kt)                                          \
  {                                                               \
    char* _d = smem + (buf) * 65536 + 32768 + w * 4096;           \
    const long _ko = (long)(kt) * 64;                             \
    g2l16(gB + _ko, _d);                                          \
    g2l16(gB + K8 + _ko, _d + 1024);                              \
    g2l16(gB + 2 * K8 + _ko, _d + 2048);                          \
    g2l16(gB + 3 * K8 + _ko, _d + 3072);                          \
  }

  STAGE_A(0, 0); STAGE_B(0, 0);
  FENCE();
  asm volatile("s_waitcnt vmcnt(0)" ::: "memory");
  __builtin_amdgcn_s_barrier();
  FENCE();

  for (int kt = 0; kt < KT; ++kt) {
    const char* sb = smem + (kt & 1) * 65536;
    const int nb = (kt + 1) & 1;
    const bool ds = (kt + 1) < KT;

    bf16x8 bfr[4][2];

    // ---- phase 0: B all 8 frags + A m-frags 0..3; stage A(t+1); 32 MFMA ----
    {
      bf16x8 a0[4][2];
#pragma unroll
      for (int j = 0; j < 4; ++j) {
        bfr[j][0] = *(const bf16x8*)(sb + bRow + j * 2048 + sx0);
        bfr[j][1] = *(const bf16x8*)(sb + bRow + j * 2048 + sx1);
      }
#pragma unroll
      for (int i = 0; i < 4; ++i) {
        a0[i][0] = *(const bf16x8*)(sb + aRow + i * 2048 + sx0);
        a0[i][1] = *(const bf16x8*)(sb + aRow + i * 2048 + sx1);
      }
      if (ds) STAGE_A(nb, kt + 1);
      FENCE();
      __builtin_amdgcn_s_barrier();
      FENCE();
      __builtin_amdgcn_s_setprio(1);
#pragma unroll
      for (int i = 0; i < 4; ++i)
#pragma unroll
        for (int j = 0; j < 4; ++j) {
          acc[i][j] = mfma16(a0[i][0], bfr[j][0], acc[i][j]);
          acc[i][j] = mfma16(a0[i][1], bfr[j][1], acc[i][j]);
        }
      __builtin_amdgcn_s_setprio(0);
      FENCE();
      __builtin_amdgcn_s_barrier();
      FENCE();
    }

    // ---- phase 1: A m-frags 4..7; stage B(t+1); 32 MFMA; boundary wait ----
    {
      bf16x8 a1[4][2];
#pragma unroll
      for (int i = 0; i < 4; ++i) {
        a1[i][0] = *(const bf16x8*)(sb + aRow + (4 + i) * 2048 + sx0);
        a1[i][1] = *(const bf16x8*)(sb + aRow + (4 + i) * 2048 + sx1);
      }
      if (ds) STAGE_B(nb, kt + 1);
      FENCE();
      __builtin_amdgcn_s_barrier();
      FENCE();
      __builtin_amdgcn_s_setprio(1);
#pragma unroll
      for (int i = 0; i < 4; ++i)
#pragma unroll
        for (int j = 0; j < 4; ++j) {
          acc[4 + i][j] = mfma16(a1[i][0], bfr[j][0], acc[4 + i][j]);
          acc[4 + i][j] = mfma16(a1[i][1], bfr[j][1], acc[4 + i][j]);
        }
      __builtin_amdgcn_s_setprio(0);
      FENCE();
      if (ds) {
        asm volatile("s_waitcnt vmcnt(0)" ::: "memory");
      }
      __builtin_amdgcn_s_barrier();
      FENCE();
    }
  }
#undef STAGE_A
#undef STAGE_B

#pragma unroll
  for (int i = 0; i < 8; ++i)
#pragma unroll
    for (int j = 0; j < 4; ++j)
#pragma unroll
      for (int r = 0; r < 4; ++r) {
        long row = rowA0 + wm * 128 + i * 16 + lg * 4 + r;
        long col = colC0 + wn * 64 + j * 16 + lr;
        C[row * (long)N + col] = (OutT)acc[i][j][r];
      }
}

// merged QK + Vt projections
__global__ void __launch_bounds__(512, 2) gemm_qkvt(const bf16_t* __restrict__ xb,
                                                    const bf16_t* __restrict__ wqk,
                                                    bf16_t* __restrict__ qk,
                                                    const bf16_t* __restrict__ wvb,
                                                    bf16_t* __restrict__ vt) {
  extern __shared__ char smem[];
  const int id = blockIdx.x;
  if (id < 512) {
    gemm_core<bf16_t>(xb, wqk, qk, 2048, 1024, 8, 512, id, smem);
  } else {
    gemm_core<bf16_t>(wvb, xb, vt, 16384, 1024, 64, 256, id - 512, smem);
  }
}

// output projection
__global__ void __launch_bounds__(512, 2) gemm_out(const bf16_t* __restrict__ att,
                                                   const bf16_t* __restrict__ wob,
                                                   float* __restrict__ out) {
  extern __shared__ char smem[];
  gemm_core<float>(att, wob, out, 1024, 1024, 4, 256, blockIdx.x, smem);
}

// ---------------- sliding-window attention (round-10 proven: staged K/V,
// pipelined counted-vmcnt staging, no-max-sub softmax) ----------------
__global__ void __launch_bounds__(512, 4) swa3(const bf16_t* __restrict__ QK,
                                               const bf16_t* __restrict__ VT,
                                               const float* __restrict__ amask,
                                               bf16_t* __restrict__ Att) {
  extern __shared__ char lds[];
  bf16_t* Ks = (bf16_t*)lds;
  bf16_t* Vs = (bf16_t*)(lds + 16384);
  float* bias = (float*)(lds + 32768);          // 3*128 f32 = 1536 B
  const int t = threadIdx.x, w = t >> 6, l = t & 63, lr = l & 15, lg = l >> 4;
  char* Psw = lds + 34304 + w * 4352;

  const int idx = (blockIdx.x & 7) * 256 + (blockIdx.x >> 3);
  const int n = idx & 31, h = (idx >> 5) & 15, b = idx >> 9;
  const long rowQ = (long)b * 4096 + n * 128;

  bf16x8 qf[2];
#pragma unroll
  for (int ks = 0; ks < 2; ++ks)
    qf[ks] = *(const bf16x8*)&QK[(rowQ + w * 16 + lr) * 2048 + h * 64 + ks * 32 + lg * 8];

  f32x4 oT[4] = {};
  float l_run = 0.f;

  const int kcLo = (n > 0) ? n - 1 : 0;
  const int kcHi = (n < 31) ? n + 1 : 31;
  const long kbase0 = (long)b * 4096 + (long)kcLo * 128;
  const int nch = kcHi - kcLo + 1;

  const int kcol = ((t & 7) ^ ((t >> 3) & 7)) * 8;
  const bf16_t* gK0 = QK + (kbase0 + (t >> 3)) * 2048 + 1024 + h * 64 + kcol;
  const int vrow = t >> 4;
  const int vcol = ((t & 15) ^ ((t >> 4) & 15)) * 8;
  const bf16_t* gV0 = VT + ((long)h * 64 + vrow) * 16384 + kbase0 + vcol;

  bf16_t* lK0 = Ks + t * 8;
  bf16_t* lK1 = Ks + 4096 + t * 8;
  bf16_t* lV0 = Vs + t * 8;
  bf16_t* lV1 = Vs + 4096 + t * 8;

#define STAGE_K(cc)                                               \
  {                                                               \
    const bf16_t* _k = gK0 + (long)(cc) * 128 * 2048;             \
    g2l16(_k, lK0);                                               \
    g2l16(_k + (long)64 * 2048, lK1);                             \
  }
#define STAGE_V(cc)                                               \
  {                                                               \
    const bf16_t* _v = gV0 + (long)(cc) * 128;                    \
    g2l16(_v, lV0);                                               \
    g2l16(_v + (long)32 * 16384, lV1);                            \
  }

  STAGE_K(0); STAGE_V(0);
  if (t < nch * 32) {
    float4 mv = *(const float4*)(amask + kbase0 + t * 4);
    float4 bv;
    bv.x = mv.x > 0.f ? 0.f : -1e30f;
    bv.y = mv.y > 0.f ? 0.f : -1e30f;
    bv.z = mv.z > 0.f ? 0.f : -1e30f;
    bv.w = mv.w > 0.f ? 0.f : -1e30f;
    *(float4*)&bias[t * 4] = bv;
  }
  FENCE();
  asm volatile("s_waitcnt vmcnt(0)" ::: "memory");
  __syncthreads();

  const float c1 = 0.18033688011112042f;  // 0.125 * log2(e)

  for (int c = 0; c < nch; ++c) {
    const bool more = (c + 1) < nch;

    // ---- QK^T -> S^T (lane: q=lr, keys = kb*16 + lg*4 + r) ----
    f32x4 s[8];
#pragma unroll
    for (int kb = 0; kb < 8; ++kb) {
      f32x4 z = {};
#pragma unroll
      for (int ks = 0; ks < 2; ++ks) {
        bf16x8 kA = *(const bf16x8*)&Ks[(kb * 16 + lr) * 64 + (((ks * 4 + lg) ^ (lr & 7)) * 8)];
        z = mfma16(kA, qf[ks], z);
      }
      s[kb] = z;
    }
    FENCE();
    __builtin_amdgcn_s_barrier();
    if (more) STAGE_K(c + 1);

    // ---- softmax numerator: p = 2^(s*c1 + bias'), no max subtraction ----
    float rs = 0.f;
#pragma unroll
    for (int kb = 0; kb < 8; ++kb) {
      f32x4 bb = *(const f32x4*)&bias[c * 128 + kb * 16 + lg * 4];
#pragma unroll
      for (int r = 0; r < 4; ++r) {
        float p = __builtin_amdgcn_exp2f(s[kb][r] * c1 + bb[r]);
        s[kb][r] = p;
        rs += p;
      }
    }
    rs += __shfl_xor(rs, 16);
    rs += __shfl_xor(rs, 32);
    l_run += rs;

    // ---- P^T -> per-wave LDS (b64), wave-level fence before cross-lane reads ----
#pragma unroll
    for (int kb = 0; kb < 8; ++kb) {
      bf16x4 pv;
      pv[0] = (bf16_t)s[kb][0]; pv[1] = (bf16_t)s[kb][1];
      pv[2] = (bf16_t)s[kb][2]; pv[3] = (bf16_t)s[kb][3];
      *(bf16x4*)(Psw + lr * 272 + kb * 32 + lg * 8) = pv;
    }
    asm volatile("s_waitcnt lgkmcnt(0)" ::: "memory");
    __builtin_amdgcn_sched_barrier(0);

    FENCE();
    if (more) asm volatile("s_waitcnt vmcnt(2)" ::: "memory");
    else      asm volatile("s_waitcnt vmcnt(0)" ::: "memory");
    __builtin_amdgcn_s_barrier();

    // ---- PV: O^T[d,q] += V^T x P^T ----
#pragma unroll
    for (int ks = 0; ks < 4; ++ks) {
      bf16x8 pB = *(const bf16x8*)(Psw + lr * 272 + ks * 64 + lg * 16);
#pragma unroll
      for (int df = 0; df < 4; ++df) {
        bf16x8 vA = *(const bf16x8*)&Vs[(df * 16 + lr) * 128 + (((ks * 4 + lg) ^ lr) * 8)];
        oT[df] = mfma16(vA, pB, oT[df]);
      }
    }
    FENCE();
    __builtin_amdgcn_s_barrier();
    if (more) {
      STAGE_V(c + 1);
      FENCE();
      asm volatile("s_waitcnt vmcnt(2)" ::: "memory");
      __builtin_amdgcn_s_barrier();
    }
  }
#undef STAGE_K
#undef STAGE_V

  // ---- epilogue: normalize, transpose O^T via per-wave Psw, coalesced store ----
  float inv = 1.f / l_run;
#pragma unroll
  for (int df = 0; df < 4; ++df) {
    bf16x4 ov;
#pragma unroll
    for (int r = 0; r < 4; ++r) ov[r] = (bf16_t)(oT[df][r] * inv);
    *(bf16x4*)(Psw + lr * 272 + df * 32 + lg * 8) = ov;
  }
  asm volatile("s_waitcnt lgkmcnt(0)" ::: "memory");
  __builtin_amdgcn_sched_barrier(0);
  const char* myP = lds + 34304 + w * 4352;
  bf16x8 r0 = *(const bf16x8*)(myP + (l >> 2) * 272 + (l & 3) * 32);
  bf16x8 r1 = *(const bf16x8*)(myP + (l >> 2) * 272 + (l & 3) * 32 + 16);
  long orow = rowQ + w * 16 + (l >> 2);
  bf16_t* op = Att + orow * 1024 + h * 64 + (l & 3) * 16;
  *(bf16x8*)op = r0;
  *(bf16x8*)(op + 8) = r1;
}

// ---------------- launch ----------------
extern "C" void kernel_launch(void* const* d_in, const int* in_sizes, int n_in,
                              void* d_out, int out_size, void* d_ws, size_t ws_size,
                              hipStream_t stream) {
  const float* x  = (const float*)d_in[0];
  const float* am = (const float*)d_in[1];
  const float* Wq = (const float*)d_in[2];
  const float* Wk = (const float*)d_in[3];
  const float* Wv = (const float*)d_in[4];
  const float* Wo = (const float*)d_in[5];
  float* out = (float*)d_out;

  char* ws = (char*)d_ws;
  bf16_t* qk  = (bf16_t*)ws;                        // [16384,2048] = 67108864 B
  bf16_t* vt  = (bf16_t*)(ws + 67108864);           // [1024,16384] = 33554432 B
  bf16_t* xbx = (bf16_t*)(ws + 100663296);          // [16384,1024] bf16 x; reused as attended
  bf16_t* wqk = (bf16_t*)(ws + 134217728);          // [2048,1024] rows: Wq, Wk
  bf16_t* wvb = (bf16_t*)(ws + 138412032);          // [1024,1024] Wv
  bf16_t* wob = (bf16_t*)(ws + 140509184);          // [1024,1024] Wo

  const int kSmemG = 131072;  // 2 x 64KB double buffer
  hipFuncSetAttribute(reinterpret_cast<const void*>(&gemm_qkvt),
                      hipFuncAttributeMaxDynamicSharedMemorySize, kSmemG);
  hipFuncSetAttribute(reinterpret_cast<const void*>(&gemm_out),
                      hipFuncAttributeMaxDynamicSharedMemorySize, kSmemG);
  const int kSmemS = 69120;  // Ks 16K + Vs 16K + bias 1.5K + Psw 8*4352
  hipFuncSetAttribute(reinterpret_cast<const void*>(&swa3),
                      hipFuncAttributeMaxDynamicSharedMemorySize, kSmemS);

  cvt_all<<<10240, 256, 0, stream>>>(x, Wq, Wk, Wv, Wo, xbx, wqk, wvb, wob);

  // merged: QK projection (512 blocks) + V^T projection (256 blocks)
  gemm_qkvt<<<768, 512, kSmemG, stream>>>(xbx, wqk, qk, wvb, vt);

  // local attention -> attended [16384,1024] bf16 (overwrites xbx)
  swa3<<<2048, 512, kSmemS, stream>>>(qk, vt, am, xbx);

  // output projection -> d_out f32
  gemm_out<<<256, 512, kSmemG, stream>>>(xbx, wob, out);
}

// Round 15
// 206.951 us; speedup vs baseline: 1.6442x; 1.0462x over previous
//
#include <hip/hip_runtime.h>
#include <stdint.h>

typedef __bf16 bf16_t;
typedef __bf16 bf16x8 __attribute__((ext_vector_type(8)));
typedef __bf16 bf16x4 __attribute__((ext_vector_type(4)));
typedef float f32x4 __attribute__((ext_vector_type(4)));

__device__ __forceinline__ f32x4 mfma16(bf16x8 a, bf16x8 b, f32x4 c) {
  return __builtin_amdgcn_mfma_f32_16x16x32_bf16(a, b, c, 0, 0, 0);
}

__device__ __forceinline__ void g2l16(const void* g, void* l) {
  __builtin_amdgcn_global_load_lds((const __attribute__((address_space(1))) void*)g,
                                   (__attribute__((address_space(3))) void*)l, 16, 0, 0);
}

#define FENCE() asm volatile("" ::: "memory")

// ---------------- all f32 -> bf16 converts, one launch ----------------
__global__ void __launch_bounds__(256) cvt_all(const float* __restrict__ x,
                                               const float* __restrict__ Wq,
                                               const float* __restrict__ Wk,
                                               const float* __restrict__ Wv,
                                               const float* __restrict__ Wo,
                                               bf16_t* __restrict__ xb,
                                               bf16_t* __restrict__ wqk,
                                               bf16_t* __restrict__ wvb,
                                               bf16_t* __restrict__ wob) {
  const int id = blockIdx.x;
  const float* src;
  bf16_t* dst;
  long off;
  if (id < 8192) {
    src = x; dst = xb; off = (long)id;
  } else {
    const int seg = (id - 8192) >> 9;
    off = (id - 8192) & 511;
    if (seg == 0)      { src = Wq; dst = wqk; }
    else if (seg == 1) { src = Wk; dst = wqk + 1048576; }
    else if (seg == 2) { src = Wv; dst = wvb; }
    else               { src = Wo; dst = wob; }
  }
  long i = (off * 256 + threadIdx.x) * 8;
  float4 f0 = *(const float4*)(src + i);
  float4 f1 = *(const float4*)(src + i + 4);
  bf16x8 v;
  v[0] = (bf16_t)f0.x; v[1] = (bf16_t)f0.y; v[2] = (bf16_t)f0.z; v[3] = (bf16_t)f0.w;
  v[4] = (bf16_t)f1.x; v[5] = (bf16_t)f1.y; v[6] = (bf16_t)f1.z; v[7] = (bf16_t)f1.w;
  *(bf16x8*)(dst + i) = v;
}

// ------- 256x256 2-phase GEMM core (round-12 measured body, unchanged) -------
template <typename OutT>
__device__ __forceinline__ void gemm_core(const bf16_t* __restrict__ A,
                                          const bf16_t* __restrict__ Bt,
                                          OutT* __restrict__ C,
                                          int N, int K, int NBN, int nseg, int flat,
                                          char* smem) {
  const int t = threadIdx.x;
  const int w = t >> 6, l = t & 63;
  const int lr = l & 15, lg = l >> 4;
  const int wm = w >> 2, wn = w & 3;

  const int swz = (flat & 7) * (nseg >> 3) + (flat >> 3);
  const int bm = swz / NBN, bn = swz % NBN;
  const long rowA0 = (long)bm * 256;
  const long colC0 = (long)bn * 256;
  const int KT = K >> 6;

  const int colSwz = ((l & 7) ^ (l >> 3)) * 8;
  const bf16_t* gA = A + (rowA0 + w * 32 + (l >> 3)) * (long)K + colSwz;
  const bf16_t* gB = Bt + (colC0 + w * 32 + (l >> 3)) * (long)K + colSwz;
  const long K8 = (long)K * 8;

  const int sx0 = (lg ^ (lr & 7)) * 16;
  const int sx1 = ((4 + lg) ^ (lr & 7)) * 16;
  const int aRow = (wm * 128 + lr) * 128;
  const int bRow = 32768 + (wn * 64 + lr) * 128;

  f32x4 acc[8][4] = {};

#define STAGE_A(buf, kt)                                          \
  {                                                               \
    char* _d = smem + (buf) * 65536 + w * 4096;                   \
    const long _ko = (long)(kt) * 64;                             \
    g2l16(gA + _ko, _d);                                          \
    g2l16(gA + K8 + _ko, _d + 1024);                              \
    g2l16(gA + 2 * K8 + _ko, _d + 2048);                          \
    g2l16(gA + 3 * K8 + _ko, _d + 3072);                          \
  }
#define STAGE_B(buf, kt)                                          \
  {                                                               \
    char* _d = smem + (buf) * 65536 + 32768 + w * 4096;           \
    const long _ko = (long)(kt) * 64;                             \
    g2l16(gB + _ko, _d);                                          \
    g2l16(gB + K8 + _ko, _d + 1024);                              \
    g2l16(gB + 2 * K8 + _ko, _d + 2048);                          \
    g2l16(gB + 3 * K8 + _ko, _d + 3072);                          \
  }

  STAGE_A(0, 0); STAGE_B(0, 0);
  FENCE();
  asm volatile("s_waitcnt vmcnt(0)" ::: "memory");
  __builtin_amdgcn_s_barrier();
  FENCE();

  for (int kt = 0; kt < KT; ++kt) {
    const char* sb = smem + (kt & 1) * 65536;
    const int nb = (kt + 1) & 1;
    const bool ds = (kt + 1) < KT;

    bf16x8 bfr[4][2];

    {
      bf16x8 a0[4][2];
#pragma unroll
      for (int j = 0; j < 4; ++j) {
        bfr[j][0] = *(const bf16x8*)(sb + bRow + j * 2048 + sx0);
        bfr[j][1] = *(const bf16x8*)(sb + bRow + j * 2048 + sx1);
      }
#pragma unroll
      for (int i = 0; i < 4; ++i) {
        a0[i][0] = *(const bf16x8*)(sb + aRow + i * 2048 + sx0);
        a0[i][1] = *(const bf16x8*)(sb + aRow + i * 2048 + sx1);
      }
      if (ds) STAGE_A(nb, kt + 1);
      FENCE();
      __builtin_amdgcn_s_barrier();
      FENCE();
      __builtin_amdgcn_s_setprio(1);
#pragma unroll
      for (int i = 0; i < 4; ++i)
#pragma unroll
        for (int j = 0; j < 4; ++j) {
          acc[i][j] = mfma16(a0[i][0], bfr[j][0], acc[i][j]);
          acc[i][j] = mfma16(a0[i][1], bfr[j][1], acc[i][j]);
        }
      __builtin_amdgcn_s_setprio(0);
      FENCE();
      __builtin_amdgcn_s_barrier();
      FENCE();
    }

    {
      bf16x8 a1[4][2];
#pragma unroll
      for (int i = 0; i < 4; ++i) {
        a1[i][0] = *(const bf16x8*)(sb + aRow + (4 + i) * 2048 + sx0);
        a1[i][1] = *(const bf16x8*)(sb + aRow + (4 + i) * 2048 + sx1);
      }
      if (ds) STAGE_B(nb, kt + 1);
      FENCE();
      __builtin_amdgcn_s_barrier();
      FENCE();
      __builtin_amdgcn_s_setprio(1);
#pragma unroll
      for (int i = 0; i < 4; ++i)
#pragma unroll
        for (int j = 0; j < 4; ++j) {
          acc[4 + i][j] = mfma16(a1[i][0], bfr[j][0], acc[4 + i][j]);
          acc[4 + i][j] = mfma16(a1[i][1], bfr[j][1], acc[4 + i][j]);
        }
      __builtin_amdgcn_s_setprio(0);
      FENCE();
      if (ds) {
        asm volatile("s_waitcnt vmcnt(0)" ::: "memory");
      }
      __builtin_amdgcn_s_barrier();
      FENCE();
    }
  }
#undef STAGE_A
#undef STAGE_B

#pragma unroll
  for (int i = 0; i < 8; ++i)
#pragma unroll
    for (int j = 0; j < 4; ++j)
#pragma unroll
      for (int r = 0; r < 4; ++r) {
        long row = rowA0 + wm * 128 + i * 16 + lg * 4 + r;
        long col = colC0 + wn * 64 + j * 16 + lr;
        C[row * (long)N + col] = (OutT)acc[i][j][r];
      }
}

// merged QK + Vt projections
__global__ void __launch_bounds__(512, 2) gemm_qkvt(const bf16_t* __restrict__ xb,
                                                    const bf16_t* __restrict__ wqk,
                                                    bf16_t* __restrict__ qk,
                                                    const bf16_t* __restrict__ wvb,
                                                    bf16_t* __restrict__ vt) {
  extern __shared__ char smem[];
  const int id = blockIdx.x;
  if (id < 512) {
    gemm_core<bf16_t>(xb, wqk, qk, 2048, 1024, 8, 512, id, smem);
  } else {
    gemm_core<bf16_t>(wvb, xb, vt, 16384, 1024, 64, 256, id - 512, smem);
  }
}

// output projection
__global__ void __launch_bounds__(512, 2) gemm_out(const bf16_t* __restrict__ att,
                                                   const bf16_t* __restrict__ wob,
                                                   float* __restrict__ out) {
  extern __shared__ char smem[];
  gemm_core<float>(att, wob, out, 1024, 1024, 4, 256, blockIdx.x, smem);
}

// ---------------- sliding-window attention (round-10/12 proven swa3: staged K/V,
// pipelined counted-vmcnt staging, no-max-sub softmax) ----------------
__global__ void __launch_bounds__(512, 4) swa3(const bf16_t* __restrict__ QK,
                                               const bf16_t* __restrict__ VT,
                                               const float* __restrict__ amask,
                                               bf16_t* __restrict__ Att) {
  extern __shared__ char lds[];
  bf16_t* Ks = (bf16_t*)lds;
  bf16_t* Vs = (bf16_t*)(lds + 16384);
  float* bias = (float*)(lds + 32768);          // 3*128 f32 = 1536 B
  const int t = threadIdx.x, w = t >> 6, l = t & 63, lr = l & 15, lg = l >> 4;
  char* Psw = lds + 34304 + w * 4352;

  const int idx = (blockIdx.x & 7) * 256 + (blockIdx.x >> 3);
  const int n = idx & 31, h = (idx >> 5) & 15, b = idx >> 9;
  const long rowQ = (long)b * 4096 + n * 128;

  bf16x8 qf[2];
#pragma unroll
  for (int ks = 0; ks < 2; ++ks)
    qf[ks] = *(const bf16x8*)&QK[(rowQ + w * 16 + lr) * 2048 + h * 64 + ks * 32 + lg * 8];

  f32x4 oT[4] = {};
  float l_run = 0.f;

  const int kcLo = (n > 0) ? n - 1 : 0;
  const int kcHi = (n < 31) ? n + 1 : 31;
  const long kbase0 = (long)b * 4096 + (long)kcLo * 128;
  const int nch = kcHi - kcLo + 1;

  const int kcol = ((t & 7) ^ ((t >> 3) & 7)) * 8;
  const bf16_t* gK0 = QK + (kbase0 + (t >> 3)) * 2048 + 1024 + h * 64 + kcol;
  const int vrow = t >> 4;
  const int vcol = ((t & 15) ^ ((t >> 4) & 15)) * 8;
  const bf16_t* gV0 = VT + ((long)h * 64 + vrow) * 16384 + kbase0 + vcol;

  bf16_t* lK0 = Ks + t * 8;
  bf16_t* lK1 = Ks + 4096 + t * 8;
  bf16_t* lV0 = Vs + t * 8;
  bf16_t* lV1 = Vs + 4096 + t * 8;

#define STAGE_K(cc)                                               \
  {                                                               \
    const bf16_t* _k = gK0 + (long)(cc) * 128 * 2048;             \
    g2l16(_k, lK0);                                               \
    g2l16(_k + (long)64 * 2048, lK1);                             \
  }
#define STAGE_V(cc)                                               \
  {                                                               \
    const bf16_t* _v = gV0 + (long)(cc) * 128;                    \
    g2l16(_v, lV0);                                               \
    g2l16(_v + (long)32 * 16384, lV1);                            \
  }

  STAGE_K(0); STAGE_V(0);
  if (t < nch * 32) {
    float4 mv = *(const float4*)(amask + kbase0 + t * 4);
    float4 bv;
    bv.x = mv.x > 0.f ? 0.f : -1e30f;
    bv.y = mv.y > 0.f ? 0.f : -1e30f;
    bv.z = mv.z > 0.f ? 0.f : -1e30f;
    bv.w = mv.w > 0.f ? 0.f : -1e30f;
    *(float4*)&bias[t * 4] = bv;
  }
  FENCE();
  asm volatile("s_waitcnt vmcnt(0)" ::: "memory");
  __syncthreads();

  const float c1 = 0.18033688011112042f;  // 0.125 * log2(e)

  for (int c = 0; c < nch; ++c) {
    const bool more = (c + 1) < nch;

    // ---- QK^T -> S^T (lane: q=lr, keys = kb*16 + lg*4 + r) ----
    f32x4 s[8];
#pragma unroll
    for (int kb = 0; kb < 8; ++kb) {
      f32x4 z = {};
#pragma unroll
      for (int ks = 0; ks < 2; ++ks) {
        bf16x8 kA = *(const bf16x8*)&Ks[(kb * 16 + lr) * 64 + (((ks * 4 + lg) ^ (lr & 7)) * 8)];
        z = mfma16(kA, qf[ks], z);
      }
      s[kb] = z;
    }
    FENCE();
    __builtin_amdgcn_s_barrier();
    if (more) STAGE_K(c + 1);

    // ---- softmax numerator: p = 2^(s*c1 + bias'), no max subtraction ----
    float rs = 0.f;
#pragma unroll
    for (int kb = 0; kb < 8; ++kb) {
      f32x4 bb = *(const f32x4*)&bias[c * 128 + kb * 16 + lg * 4];
#pragma unroll
      for (int r = 0; r < 4; ++r) {
        float p = __builtin_amdgcn_exp2f(s[kb][r] * c1 + bb[r]);
        s[kb][r] = p;
        rs += p;
      }
    }
    rs += __shfl_xor(rs, 16);
    rs += __shfl_xor(rs, 32);
    l_run += rs;

    // ---- P^T -> per-wave LDS (b64), wave-level fence before cross-lane reads ----
#pragma unroll
    for (int kb = 0; kb < 8; ++kb) {
      bf16x4 pv;
      pv[0] = (bf16_t)s[kb][0]; pv[1] = (bf16_t)s[kb][1];
      pv[2] = (bf16_t)s[kb][2]; pv[3] = (bf16_t)s[kb][3];
      *(bf16x4*)(Psw + lr * 272 + kb * 32 + lg * 8) = pv;
    }
    asm volatile("s_waitcnt lgkmcnt(0)" ::: "memory");
    __builtin_amdgcn_sched_barrier(0);

    FENCE();
    if (more) asm volatile("s_waitcnt vmcnt(2)" ::: "memory");
    else      asm volatile("s_waitcnt vmcnt(0)" ::: "memory");
    __builtin_amdgcn_s_barrier();

    // ---- PV: O^T[d,q] += V^T x P^T ----
#pragma unroll
    for (int ks = 0; ks < 4; ++ks) {
      bf16x8 pB = *(const bf16x8*)(Psw + lr * 272 + ks * 64 + lg * 16);
#pragma unroll
      for (int df = 0; df < 4; ++df) {
        bf16x8 vA = *(const bf16x8*)&Vs[(df * 16 + lr) * 128 + (((ks * 4 + lg) ^ lr) * 8)];
        oT[df] = mfma16(vA, pB, oT[df]);
      }
    }
    FENCE();
    __builtin_amdgcn_s_barrier();
    if (more) {
      STAGE_V(c + 1);
      FENCE();
      asm volatile("s_waitcnt vmcnt(2)" ::: "memory");
      __builtin_amdgcn_s_barrier();
    }
  }
#undef STAGE_K
#undef STAGE_V

  // ---- epilogue: normalize, transpose O^T via per-wave Psw, coalesced store ----
  float inv = 1.f / l_run;
#pragma unroll
  for (int df = 0; df < 4; ++df) {
    bf16x4 ov;
#pragma unroll
    for (int r = 0; r < 4; ++r) ov[r] = (bf16_t)(oT[df][r] * inv);
    *(bf16x4*)(Psw + lr * 272 + df * 32 + lg * 8) = ov;
  }
  asm volatile("s_waitcnt lgkmcnt(0)" ::: "memory");
  __builtin_amdgcn_sched_barrier(0);
  const char* myP = lds + 34304 + w * 4352;
  bf16x8 r0 = *(const bf16x8*)(myP + (l >> 2) * 272 + (l & 3) * 32);
  bf16x8 r1 = *(const bf16x8*)(myP + (l >> 2) * 272 + (l & 3) * 32 + 16);
  long orow = rowQ + w * 16 + (l >> 2);
  bf16_t* op = Att + orow * 1024 + h * 64 + (l & 3) * 16;
  *(bf16x8*)op = r0;
  *(bf16x8*)(op + 8) = r1;
}

// ---------------- launch ----------------
extern "C" void kernel_launch(void* const* d_in, const int* in_sizes, int n_in,
                              void* d_out, int out_size, void* d_ws, size_t ws_size,
                              hipStream_t stream) {
  const float* x  = (const float*)d_in[0];
  const float* am = (const float*)d_in[1];
  const float* Wq = (const float*)d_in[2];
  const float* Wk = (const float*)d_in[3];
  const float* Wv = (const float*)d_in[4];
  const float* Wo = (const float*)d_in[5];
  float* out = (float*)d_out;

  char* ws = (char*)d_ws;
  bf16_t* qk  = (bf16_t*)ws;                        // [16384,2048] = 67108864 B
  bf16_t* vt  = (bf16_t*)(ws + 67108864);           // [1024,16384] = 33554432 B
  bf16_t* xbx = (bf16_t*)(ws + 100663296);          // [16384,1024] bf16 x; reused as attended
  bf16_t* wqk = (bf16_t*)(ws + 134217728);          // [2048,1024] rows: Wq, Wk
  bf16_t* wvb = (bf16_t*)(ws + 138412032);          // [1024,1024] Wv
  bf16_t* wob = (bf16_t*)(ws + 140509184);          // [1024,1024] Wo

  const int kSmemG = 131072;  // 2 x 64KB double buffer
  hipFuncSetAttribute(reinterpret_cast<const void*>(&gemm_qkvt),
                      hipFuncAttributeMaxDynamicSharedMemorySize, kSmemG);
  hipFuncSetAttribute(reinterpret_cast<const void*>(&gemm_out),
                      hipFuncAttributeMaxDynamicSharedMemorySize, kSmemG);
  const int kSmemS = 69120;  // Ks 16K + Vs 16K + bias 1.5K + Psw 8*4352
  hipFuncSetAttribute(reinterpret_cast<const void*>(&swa3),
                      hipFuncAttributeMaxDynamicSharedMemorySize, kSmemS);

  cvt_all<<<10240, 256, 0, stream>>>(x, Wq, Wk, Wv, Wo, xbx, wqk, wvb, wob);

  // merged: QK projection (512 blocks) + V^T projection (256 blocks)
  gemm_qkvt<<<768, 512, kSmemG, stream>>>(xbx, wqk, qk, wvb, vt);

  // local attention -> attended [16384,1024] bf16 (overwrites xbx)
  swa3<<<2048, 512, kSmemS, stream>>>(qk, vt, am, xbx);

  // output projection -> d_out f32
  gemm_out<<<256, 512, kSmemG, stream>>>(xbx, wob, out);
}